// Round 6
// baseline (218.559 us; speedup 1.0000x reference)
//
#include <hip/hip_runtime.h>
#include <math.h>

#define NB 32
#define NT 4096
#define ND 1024

typedef float f32x4 __attribute__((ext_vector_type(4)));

// ---------------------------------------------------------------------------
// Single fused kernel. Grid (chunks=16, NB), 256 threads = 4 waves.
// Phase A (every WG): online-softmax over its 256-row chunk (identical to the
// R5 pass1 hot loop: register-double-buffered 2-row stages, branchless
// update, LDS-staged pax). Writes (ctx, m, l) to workspace + raw pax to the
// ax slot of d_out, then release-fence + atomicAdd(count[b]).
// Phase B (the last WG of each batch): acquire-fence, computes (M, 1/L) from
// the 16 (m, l) pairs, rewrites pax -> ax in place, merges the 16 chunk
// contexts -> sx. Split-K last-block pattern; no spin-waits, so safe under
// any dispatch order (G16), cross-XCD visibility via device-scope
// atomics/fences (G12).
// ---------------------------------------------------------------------------

#define LOAD2(P, S_) do {                                                     \
    const f32x4* er0_ = ehb + (size_t)(row0 + 2*(S_)) * (ND/4);               \
    const f32x4* er1_ = er0_ + (ND/4);                                        \
    P##_e0 = er0_[0*64+lane]; P##_e1 = er0_[1*64+lane];                       \
    P##_e2 = er0_[2*64+lane]; P##_e3 = er0_[3*64+lane];                       \
    P##_f0 = er1_[0*64+lane]; P##_f1 = er1_[1*64+lane];                       \
    P##_f2 = er1_[2*64+lane]; P##_f3 = er1_[3*64+lane];                       \
} while (0)

#define COMPUTE2(P, S_) do {                                                  \
    f32x4 p0_ = P##_e0*dv0 + P##_e1*dv1 + P##_e2*dv2 + P##_e3*dv3;            \
    f32x4 p1_ = P##_f0*dv0 + P##_f1*dv1 + P##_f2*dv2 + P##_f3*dv3;            \
    float s0_ = p0_.x + p0_.y + p0_.z + p0_.w;                                \
    float s1_ = p1_.x + p1_.y + p1_.z + p1_.w;                                \
    _Pragma("unroll")                                                         \
    for (int off_ = 32; off_ > 0; off_ >>= 1) {                               \
        s0_ += __shfl_xor(s0_, off_, 64);                                     \
        s1_ += __shfl_xor(s1_, off_, 64);                                     \
    }                                                                         \
    if (lane == 0) {                                                          \
        s_pax[wave * rows_per_wave + 2*(S_)]     = s0_;                       \
        s_pax[wave * rows_per_wave + 2*(S_) + 1] = s1_;                       \
    }                                                                         \
    const float mn_ = fmaxf(m, fmaxf(s0_, s1_));                              \
    const float sc_ = __expf(m  - mn_);                                       \
    const float w0_ = __expf(s0_ - mn_);                                      \
    const float w1_ = __expf(s1_ - mn_);                                      \
    m = mn_;                                                                  \
    l = l*sc_ + w0_ + w1_;                                                    \
    a0 = a0*sc_ + w0_*P##_e0 + w1_*P##_f0;                                    \
    a1 = a1*sc_ + w0_*P##_e1 + w1_*P##_f1;                                    \
    a2 = a2*sc_ + w0_*P##_e2 + w1_*P##_f2;                                    \
    a3 = a3*sc_ + w0_*P##_e3 + w1_*P##_f3;                                    \
} while (0)

__global__ __launch_bounds__(256) void prodattn_fused(
    const float* __restrict__ eh,
    const float* __restrict__ dhx,
    float* __restrict__ sx_out,    // [B, D]
    float* __restrict__ ax_out,    // [B, T] (pax staging, then ax)
    float* __restrict__ ctx_out,   // [B, chunks, D]
    float* __restrict__ m_out,     // [B, chunks]
    float* __restrict__ l_out,     // [B, chunks]
    unsigned int* __restrict__ count,  // [B]
    int chunks, int rows_per_wave)
{
    const int chunk = blockIdx.x;
    const int b     = blockIdx.y;
    const int tid   = threadIdx.x;
    const int wave  = tid >> 6;
    const int lane  = tid & 63;

    __shared__ float s_pax[512];          // up to 128 rows/wave * 4 waves

    const f32x4* dhx4 = reinterpret_cast<const f32x4*>(dhx + (size_t)b * ND);
    const f32x4 dv0 = dhx4[0*64 + lane];
    const f32x4 dv1 = dhx4[1*64 + lane];
    const f32x4 dv2 = dhx4[2*64 + lane];
    const f32x4 dv3 = dhx4[3*64 + lane];

    f32x4 a0 = (f32x4)(0.f), a1 = (f32x4)(0.f), a2 = (f32x4)(0.f), a3 = (f32x4)(0.f);
    float m = -INFINITY, l = 0.f;

    const int row0 = chunk * (rows_per_wave * 4) + wave * rows_per_wave;
    const f32x4* ehb = reinterpret_cast<const f32x4*>(eh + (size_t)b * NT * ND);

    f32x4 A_e0, A_e1, A_e2, A_e3, A_f0, A_f1, A_f2, A_f3;
    f32x4 B_e0, B_e1, B_e2, B_e3, B_f0, B_f1, B_f2, B_f3;

    const int S = rows_per_wave >> 1;   // 2-row stages; S even (>=2)

    LOAD2(A, 0);
    int s = 0;
    for (; s + 2 < S; s += 2) {
        LOAD2(B, s + 1);
        COMPUTE2(A, s);
        LOAD2(A, s + 2);
        COMPUTE2(B, s + 1);
    }
    LOAD2(B, S - 1);
    COMPUTE2(A, S - 2);
    COMPUTE2(B, S - 1);

    // ---- merge 4 wave partials -> one workgroup partial ----
    __shared__ float  s_m[4];
    __shared__ float  s_l[4];
    __shared__ f32x4 s_acc[4][ND / 4];   // 16 KiB

    if (lane == 0) s_m[wave] = m;
    __syncthreads();

    // coalesced pax flush (rows_per_wave*4 consecutive rows per WG)
    {
        const int row_base = chunk * (rows_per_wave * 4);
        float* paxb = ax_out + (size_t)b * NT + row_base;
        const int n = rows_per_wave * 4;
        for (int j = tid; j < n; j += 256) paxb[j] = s_pax[j];
    }

    const float M = fmaxf(fmaxf(s_m[0], s_m[1]), fmaxf(s_m[2], s_m[3]));
    const float f = __expf(m - M);
    if (lane == 0) s_l[wave] = l * f;

    a0 *= f; a1 *= f; a2 *= f; a3 *= f;
    s_acc[wave][0*64 + lane] = a0;
    s_acc[wave][1*64 + lane] = a1;
    s_acc[wave][2*64 + lane] = a2;
    s_acc[wave][3*64 + lane] = a3;
    __syncthreads();

    f32x4 r = s_acc[0][tid] + s_acc[1][tid] + s_acc[2][tid] + s_acc[3][tid];

    reinterpret_cast<f32x4*>(ctx_out + ((size_t)b * chunks + chunk) * ND)[tid] = r;
    if (tid == 0) {
        m_out[b * chunks + chunk] = M;
        l_out[b * chunks + chunk] = s_l[0] + s_l[1] + s_l[2] + s_l[3];
    }

    // ---- release: make this WG's global writes visible, then count up ----
    __threadfence();
    __syncthreads();
    __shared__ int s_last;
    if (tid == 0) {
        const unsigned int old = atomicAdd(&count[b], 1u);
        s_last = (old == (unsigned int)(chunks - 1)) ? 1 : 0;
    }
    __syncthreads();
    if (!s_last) return;

    // =========== Phase B: this WG finalizes batch b ===========
    __threadfence();   // acquire: see all other chunks' writes

    __shared__ float sM, sInv;
    if (wave == 0) {
        float mv = (lane < chunks) ? m_out[b * chunks + lane] : -INFINITY;
        float lv = (lane < chunks) ? l_out[b * chunks + lane] : 0.f;
        float Mg = mv;
        #pragma unroll
        for (int off = 32; off > 0; off >>= 1)
            Mg = fmaxf(Mg, __shfl_xor(Mg, off, 64));
        float c = lv * __expf(mv - Mg);
        #pragma unroll
        for (int off = 32; off > 0; off >>= 1)
            c += __shfl_xor(c, off, 64);
        if (lane == 0) { sM = Mg; sInv = 1.0f / c; }
    }
    __syncthreads();
    const float Mg  = sM;
    const float inv = sInv;

    // ax rewrite: NT floats = NT/4 float4, 256 threads -> 4 iterations
    {
        f32x4* ax4 = reinterpret_cast<f32x4*>(ax_out + (size_t)b * NT);
        #pragma unroll
        for (int i = tid; i < NT / 4; i += 256) {
            f32x4 v = ax4[i];
            v.x = __expf(v.x - Mg) * inv;
            v.y = __expf(v.y - Mg) * inv;
            v.z = __expf(v.z - Mg) * inv;
            v.w = __expf(v.w - Mg) * inv;
            ax4[i] = v;
        }
    }

    // ctx merge -> sx (thread tid owns float4 index tid of D)
    {
        const f32x4* cb = reinterpret_cast<const f32x4*>(ctx_out + (size_t)b * chunks * ND);
        const float* mb = m_out + b * chunks;
        f32x4 acc0 = (f32x4)(0.f), acc1 = (f32x4)(0.f), acc2 = (f32x4)(0.f), acc3 = (f32x4)(0.f);
        int c = 0;
        for (; c + 3 < chunks; c += 4) {
            const float w0 = __expf(mb[c+0] - Mg);
            const float w1 = __expf(mb[c+1] - Mg);
            const float w2 = __expf(mb[c+2] - Mg);
            const float w3 = __expf(mb[c+3] - Mg);
            acc0 += w0 * cb[(size_t)(c+0)*(ND/4) + tid];
            acc1 += w1 * cb[(size_t)(c+1)*(ND/4) + tid];
            acc2 += w2 * cb[(size_t)(c+2)*(ND/4) + tid];
            acc3 += w3 * cb[(size_t)(c+3)*(ND/4) + tid];
        }
        for (; c < chunks; ++c) {
            const float w = __expf(mb[c] - Mg);
            acc0 += w * cb[(size_t)c*(ND/4) + tid];
        }
        f32x4 r2 = (acc0 + acc1 + acc2 + acc3) * inv;
        reinterpret_cast<f32x4*>(sx_out + (size_t)b * ND)[tid] = r2;
    }
}

extern "C" void kernel_launch(void* const* d_in, const int* in_sizes, int n_in,
                              void* d_out, int out_size, void* d_ws, size_t ws_size,
                              hipStream_t stream) {
    const float* eh  = (const float*)d_in[0];   // [B, T, D] fp32
    const float* dhx = (const float*)d_in[1];   // [B, 1, D] fp32

    float* out = (float*)d_out;
    float* sx  = out;                // [B, D]
    float* ax  = out + NB * ND;      // [B, T]

    // chunks=16 -> 512 WGs, all co-resident (no tail). Halve if ws too small.
    int chunks = 16;
    while (chunks > 1 &&
           (size_t)NB * (chunks * (ND + 2) + 1) * sizeof(float) > ws_size)
        chunks >>= 1;

    float* ctx   = (float*)d_ws;                       // [B, chunks, D]
    float* m_arr = ctx + (size_t)NB * chunks * ND;     // [B, chunks]
    float* l_arr = m_arr + (size_t)NB * chunks;        // [B, chunks]
    unsigned int* count = (unsigned int*)(l_arr + (size_t)NB * chunks);  // [B]

    // counters must be zero at every call (ws is not re-poisoned between
    // replays); async memset is graph-capture-safe.
    hipMemsetAsync(count, 0, NB * sizeof(unsigned int), stream);

    const int rows_per_wave = NT / (chunks * 4);

    dim3 grid(chunks, NB);
    prodattn_fused<<<grid, 256, 0, stream>>>(eh, dhx, sx, ax, ctx, m_arr, l_arr,
                                             count, chunks, rows_per_wave);
}

// Round 7
// 94.132 us; speedup vs baseline: 2.3218x; 2.3218x over previous
//
#include <hip/hip_runtime.h>
#include <math.h>

#define NB 32
#define NT 4096
#define ND 1024
#define SPANS 4   // ax-rewrite workgroups per batch in pass 2

typedef float f32x4 __attribute__((ext_vector_type(4)));

// ---------------------------------------------------------------------------
// Pass 1: one workgroup per (chunk, batch), 256 threads = 4 waves.
// chunks=16 -> grid 512 WGs = 2 WGs/CU, all co-resident: no ragged tail.
// Register-double-buffered 2-row stages (8 KB batches); next stage's loads
// issue before current stage's compute. Online softmax branchless. pax staged
// in LDS (keeps vmcnt clean) and flushed coalesced. eh loads NONTEMPORAL:
// pure 512 MB stream, zero reuse -> skip L2 insertion.
// ---------------------------------------------------------------------------

#define NTLOAD(p) __builtin_nontemporal_load(p)

#define LOAD2(P, S_) do {                                                     \
    const f32x4* er0_ = ehb + (size_t)(row0 + 2*(S_)) * (ND/4);               \
    const f32x4* er1_ = er0_ + (ND/4);                                        \
    P##_e0 = NTLOAD(er0_ + 0*64 + lane); P##_e1 = NTLOAD(er0_ + 1*64 + lane); \
    P##_e2 = NTLOAD(er0_ + 2*64 + lane); P##_e3 = NTLOAD(er0_ + 3*64 + lane); \
    P##_f0 = NTLOAD(er1_ + 0*64 + lane); P##_f1 = NTLOAD(er1_ + 1*64 + lane); \
    P##_f2 = NTLOAD(er1_ + 2*64 + lane); P##_f3 = NTLOAD(er1_ + 3*64 + lane); \
} while (0)

#define COMPUTE2(P, S_) do {                                                  \
    f32x4 p0_ = P##_e0*dv0 + P##_e1*dv1 + P##_e2*dv2 + P##_e3*dv3;            \
    f32x4 p1_ = P##_f0*dv0 + P##_f1*dv1 + P##_f2*dv2 + P##_f3*dv3;            \
    float s0_ = p0_.x + p0_.y + p0_.z + p0_.w;                                \
    float s1_ = p1_.x + p1_.y + p1_.z + p1_.w;                                \
    _Pragma("unroll")                                                         \
    for (int off_ = 32; off_ > 0; off_ >>= 1) {                               \
        s0_ += __shfl_xor(s0_, off_, 64);                                     \
        s1_ += __shfl_xor(s1_, off_, 64);                                     \
    }                                                                         \
    if (lane == 0) {                                                          \
        s_pax[wave * rows_per_wave + 2*(S_)]     = s0_;                       \
        s_pax[wave * rows_per_wave + 2*(S_) + 1] = s1_;                       \
    }                                                                         \
    const float mn_ = fmaxf(m, fmaxf(s0_, s1_));                              \
    const float sc_ = __expf(m  - mn_);                                       \
    const float w0_ = __expf(s0_ - mn_);                                      \
    const float w1_ = __expf(s1_ - mn_);                                      \
    m = mn_;                                                                  \
    l = l*sc_ + w0_ + w1_;                                                    \
    a0 = a0*sc_ + w0_*P##_e0 + w1_*P##_f0;                                    \
    a1 = a1*sc_ + w0_*P##_e1 + w1_*P##_f1;                                    \
    a2 = a2*sc_ + w0_*P##_e2 + w1_*P##_f2;                                    \
    a3 = a3*sc_ + w0_*P##_e3 + w1_*P##_f3;                                    \
} while (0)

__global__ __launch_bounds__(256) void prodattn_pass1(
    const float* __restrict__ eh,
    const float* __restrict__ dhx,
    float* __restrict__ pax_out,   // [B, T]
    float* __restrict__ ctx_out,   // [B, chunks, D]
    float* __restrict__ m_out,     // [B, chunks]
    float* __restrict__ l_out,     // [B, chunks]
    int chunks, int rows_per_wave)
{
    const int chunk = blockIdx.x;
    const int b     = blockIdx.y;
    const int tid   = threadIdx.x;
    const int wave  = tid >> 6;
    const int lane  = tid & 63;

    __shared__ float s_pax[512];          // up to 128 rows/wave * 4 waves

    const f32x4* dhx4 = reinterpret_cast<const f32x4*>(dhx + (size_t)b * ND);
    const f32x4 dv0 = dhx4[0*64 + lane];
    const f32x4 dv1 = dhx4[1*64 + lane];
    const f32x4 dv2 = dhx4[2*64 + lane];
    const f32x4 dv3 = dhx4[3*64 + lane];

    f32x4 a0 = (f32x4)(0.f), a1 = (f32x4)(0.f), a2 = (f32x4)(0.f), a3 = (f32x4)(0.f);
    float m = -INFINITY, l = 0.f;

    const int row0 = chunk * (rows_per_wave * 4) + wave * rows_per_wave;
    const f32x4* ehb = reinterpret_cast<const f32x4*>(eh + (size_t)b * NT * ND);

    f32x4 A_e0, A_e1, A_e2, A_e3, A_f0, A_f1, A_f2, A_f3;
    f32x4 B_e0, B_e1, B_e2, B_e3, B_f0, B_f1, B_f2, B_f3;

    const int S = rows_per_wave >> 1;   // 2-row stages; S even (>=2)

    LOAD2(A, 0);
    int s = 0;
    for (; s + 2 < S; s += 2) {
        LOAD2(B, s + 1);
        COMPUTE2(A, s);
        LOAD2(A, s + 2);
        COMPUTE2(B, s + 1);
    }
    LOAD2(B, S - 1);
    COMPUTE2(A, S - 2);
    COMPUTE2(B, S - 1);

    // ---- merge 4 wave partials -> one workgroup partial ----
    __shared__ float  s_m[4];
    __shared__ float  s_l[4];
    __shared__ f32x4 s_acc[4][ND / 4];   // 16 KiB

    if (lane == 0) s_m[wave] = m;
    __syncthreads();

    // coalesced pax flush (rows_per_wave*4 consecutive rows per WG)
    {
        const int row_base = chunk * (rows_per_wave * 4);
        float* paxb = pax_out + (size_t)b * NT + row_base;
        const int n = rows_per_wave * 4;
        for (int j = tid; j < n; j += 256) paxb[j] = s_pax[j];
    }

    const float M = fmaxf(fmaxf(s_m[0], s_m[1]), fmaxf(s_m[2], s_m[3]));
    const float f = __expf(m - M);
    if (lane == 0) s_l[wave] = l * f;

    a0 *= f; a1 *= f; a2 *= f; a3 *= f;
    s_acc[wave][0*64 + lane] = a0;
    s_acc[wave][1*64 + lane] = a1;
    s_acc[wave][2*64 + lane] = a2;
    s_acc[wave][3*64 + lane] = a3;
    __syncthreads();

    f32x4 r = s_acc[0][tid] + s_acc[1][tid] + s_acc[2][tid] + s_acc[3][tid];

    reinterpret_cast<f32x4*>(ctx_out + ((size_t)b * chunks + chunk) * ND)[tid] = r;
    if (tid == 0) {
        m_out[b * chunks + chunk] = M;
        l_out[b * chunks + chunk] = s_l[0] + s_l[1] + s_l[2] + s_l[3];
    }
}

// ---------------------------------------------------------------------------
// Pass 2: grid (NB, SPANS+1). Every WG derives (M, 1/L) from the per-chunk
// (m, l) arrays; roles 0..SPANS-1 rewrite one ax span; role SPANS merges the
// chunk contexts into sx with 4 independent accumulators.
// ---------------------------------------------------------------------------
__global__ __launch_bounds__(256) void prodattn_pass2(
    float* __restrict__ sx_out,          // [B, D]
    float* __restrict__ ax_inout,        // [B, T] (pax in, ax out)
    const float* __restrict__ ctx,       // [B, chunks, D]
    const float* __restrict__ m_arr,     // [B, chunks]
    const float* __restrict__ l_arr,     // [B, chunks]
    int chunks)
{
    const int b    = blockIdx.x;
    const int role = blockIdx.y;
    const int tid  = threadIdx.x;
    const int wave = tid >> 6;
    const int lane = tid & 63;

    __shared__ float sM, sInv;
    if (wave == 0) {
        float mv = (lane < chunks) ? m_arr[b * chunks + lane] : -INFINITY;
        float lv = (lane < chunks) ? l_arr[b * chunks + lane] : 0.f;
        float M = mv;
        #pragma unroll
        for (int off = 32; off > 0; off >>= 1)
            M = fmaxf(M, __shfl_xor(M, off, 64));
        float c = lv * __expf(mv - M);
        #pragma unroll
        for (int off = 32; off > 0; off >>= 1)
            c += __shfl_xor(c, off, 64);
        if (lane == 0) { sM = M; sInv = 1.0f / c; }
    }
    __syncthreads();
    const float M   = sM;
    const float inv = sInv;

    if (role < SPANS) {
        f32x4* ax4 = reinterpret_cast<f32x4*>(ax_inout + (size_t)b * NT)
                     + role * (NT / 4 / SPANS);
        f32x4 v = ax4[tid];
        v.x = __expf(v.x - M) * inv;
        v.y = __expf(v.y - M) * inv;
        v.z = __expf(v.z - M) * inv;
        v.w = __expf(v.w - M) * inv;
        ax4[tid] = v;
    } else {
        const f32x4* cb = reinterpret_cast<const f32x4*>(ctx + (size_t)b * chunks * ND);
        const float* mb = m_arr + b * chunks;
        f32x4 acc0 = (f32x4)(0.f), acc1 = (f32x4)(0.f), acc2 = (f32x4)(0.f), acc3 = (f32x4)(0.f);
        int c = 0;
        for (; c + 3 < chunks; c += 4) {
            const float w0 = __expf(mb[c+0] - M);
            const float w1 = __expf(mb[c+1] - M);
            const float w2 = __expf(mb[c+2] - M);
            const float w3 = __expf(mb[c+3] - M);
            acc0 += w0 * cb[(size_t)(c+0)*(ND/4) + tid];
            acc1 += w1 * cb[(size_t)(c+1)*(ND/4) + tid];
            acc2 += w2 * cb[(size_t)(c+2)*(ND/4) + tid];
            acc3 += w3 * cb[(size_t)(c+3)*(ND/4) + tid];
        }
        for (; c < chunks; ++c) {
            const float w = __expf(mb[c] - M);
            acc0 += w * cb[(size_t)c*(ND/4) + tid];
        }
        f32x4 r = (acc0 + acc1 + acc2 + acc3) * inv;
        reinterpret_cast<f32x4*>(sx_out + (size_t)b * ND)[tid] = r;
    }
}

extern "C" void kernel_launch(void* const* d_in, const int* in_sizes, int n_in,
                              void* d_out, int out_size, void* d_ws, size_t ws_size,
                              hipStream_t stream) {
    const float* eh  = (const float*)d_in[0];   // [B, T, D] fp32
    const float* dhx = (const float*)d_in[1];   // [B, 1, D] fp32

    float* out = (float*)d_out;
    float* sx  = out;                // [B, D]
    float* ax  = out + NB * ND;      // [B, T] (pax staging, then ax)

    // chunks=16 -> 512 WGs, all co-resident (no tail). Halve if ws too small.
    int chunks = 16;
    while (chunks > 1 &&
           (size_t)NB * chunks * (ND + 2) * sizeof(float) > ws_size)
        chunks >>= 1;

    float* ctx   = (float*)d_ws;                       // [B, chunks, D]
    float* m_arr = ctx + (size_t)NB * chunks * ND;     // [B, chunks]
    float* l_arr = m_arr + (size_t)NB * chunks;        // [B, chunks]

    const int rows_per_wave = NT / (chunks * 4);

    dim3 grid1(chunks, NB);
    prodattn_pass1<<<grid1, 256, 0, stream>>>(eh, dhx, ax, ctx, m_arr, l_arr,
                                              chunks, rows_per_wave);
    dim3 grid2(NB, SPANS + 1);
    prodattn_pass2<<<grid2, 256, 0, stream>>>(sx, ax, ctx, m_arr, l_arr, chunks);
}